// Round 17
// baseline (405.114 us; speedup 1.0000x reference)
//
#include <hip/hip_runtime.h>

typedef unsigned short u16;
typedef __bf16 bf16x8 __attribute__((ext_vector_type(8)));
typedef float f32x4 __attribute__((ext_vector_type(4)));

#define HN 128
#define TM 64
#define ASTRIDE 136   // 128 + 8 pad (u16), rows 16B-aligned
#define ECH 256       // edges per block in edge_kernel (4 waves x 64)

__device__ __forceinline__ u16 f2bf(float f) {
  union { float f; unsigned u; } v; v.f = f;
  unsigned r = v.u + 0x7fffu + ((v.u >> 16) & 1u);
  return (u16)(r >> 16);
}
__device__ __forceinline__ float bf2f(u16 v) {
  union { unsigned u; float f; } x; x.u = ((unsigned)v) << 16; return x.f;
}
__device__ __forceinline__ float bflo(unsigned v) {
  union { unsigned u; float f; } x; x.u = v << 16; return x.f;
}
__device__ __forceinline__ float bfhi(unsigned v) {
  union { unsigned u; float f; } x; x.u = v & 0xffff0000u; return x.f;
}
// fast silu: x * rcp(1 + exp2(-log2e*x)) — v_exp_f32/v_rcp_f32, ~1 ulp
__device__ __forceinline__ float silu_f(float x) {
  float e = __builtin_amdgcn_exp2f(-1.442695041f * x);
  return x * __builtin_amdgcn_rcpf(1.f + e);
}

// ---- pack weights into MFMA B-fragment layout: P[kg][n][8], kg=k/8 ----
// mats per layer: 0=msgW1a 1=msgW1b 2=msgW2 3=nodeW1a 4=nodeW1b 5=nodeW2
// Also zeroes deg[N] and g[G*HN].
__global__ void pack_weights(const float* __restrict__ msg_w1, const float* __restrict__ msg_w2,
                             const float* __restrict__ node_w1, const float* __restrict__ node_w2,
                             u16* __restrict__ pw, int* __restrict__ deg,
                             float* __restrict__ g, int N_, int GH) {
  int id = blockIdx.x * 256 + threadIdx.x;
  if (id < N_) deg[id] = 0;
  if (id < GH) g[id] = 0.f;
  if (id >= 4 * 6 * 16384) return;
  int l = id / (6 * 16384);
  int rem = id % (6 * 16384);
  int m = rem / 16384;
  int e = rem % 16384;
  int kg = e >> 10;
  int n = (e >> 3) & 127;
  int j = e & 7;
  int k = kg * 8 + j;
  float v = 0.f;
  switch (m) {
    case 0: v = msg_w1[(l * 257 + k) * 128 + n]; break;
    case 1: v = msg_w1[(l * 257 + 128 + k) * 128 + n]; break;
    case 2: v = msg_w2[(l * 128 + k) * 128 + n]; break;
    case 3: v = node_w1[(l * 256 + k) * 128 + n]; break;
    case 4: v = node_w1[(l * 256 + 128 + k) * 128 + n]; break;
    case 5: v = node_w2[(l * 128 + k) * 128 + n]; break;
  }
  pw[id] = f2bf(v);
}

__device__ __forceinline__ void gemm64(const u16* s_A, const u16* s_W,
                                       int w, int quad, int m16, f32x4 acc[8]) {
#pragma unroll
  for (int ks = 0; ks < 4; ks++) {
    bf16x8 a = *(const bf16x8*)&s_A[(w * 16 + m16) * ASTRIDE + ks * 32 + quad * 8];
#pragma unroll
    for (int ct = 0; ct < 8; ct++) {
      bf16x8 b = *(const bf16x8*)&s_W[(ks * 4 + quad) * 1024 + (ct * 16 + m16) * 8];
      acc[ct] = __builtin_amdgcn_mfma_f32_16x16x32_bf16(a, b, acc[ct], 0, 0, 0);
    }
  }
}

// ---- fold: Wc = msgW2 @ nodeW1b (bf16, B-frag packed), vc = msg_b2 @ nodeW1b ----
__global__ __launch_bounds__(256) void fold_kernel(
    const float* __restrict__ msg_w2, const float* __restrict__ node_w1,
    const float* __restrict__ msg_b2, const u16* __restrict__ pw,
    u16* __restrict__ pwc, float* __restrict__ vc) {
  __shared__ __align__(16) u16 s_A[TM * ASTRIDE];
  __shared__ __align__(16) u16 s_W[16384];
  const int t = threadIdx.x;
  const int w = t >> 6, lane = t & 63, quad = lane >> 4, m16 = lane & 15;
  const int b = blockIdx.x, l = b >> 1, half = b & 1;
  const int tile0 = half * 64;

  {
    int r = t >> 2, qo = (t & 3) * 32;
    const float4* src = (const float4*)(msg_w2 + (size_t)(l * 128 + tile0 + r) * 128 + qo);
    u16* dst = s_A + r * ASTRIDE + qo;
#pragma unroll
    for (int i = 0; i < 8; i++) {
      float4 v = src[i];
      ushort4 o;
      o.x = f2bf(v.x); o.y = f2bf(v.y); o.z = f2bf(v.z); o.w = f2bf(v.w);
      *(ushort4*)(dst + i * 4) = o;
    }
  }
  {
    const int4* src = (const int4*)(pw + (size_t)(l * 6 + 4) * 16384);
    int4* dst = (int4*)s_W;
#pragma unroll
    for (int i = 0; i < 8; i++) dst[t + i * 256] = src[t + i * 256];
  }
  __syncthreads();
  f32x4 acc[8];
#pragma unroll
  for (int ct = 0; ct < 8; ct++) acc[ct] = {0.f, 0.f, 0.f, 0.f};
  gemm64(s_A, s_W, w, quad, m16, acc);
#pragma unroll
  for (int ct = 0; ct < 8; ct++)
#pragma unroll
    for (int j = 0; j < 4; j++) {
      int k = tile0 + w * 16 + quad * 4 + j;
      int n = ct * 16 + m16;
      pwc[(size_t)l * 16384 + (k >> 3) * 1024 + n * 8 + (k & 7)] = f2bf(acc[ct][j]);
    }
  if (half == 0 && t < 128) {
    float s = 0.f;
    for (int np = 0; np < 128; np++)
      s += msg_b2[l * 128 + np] * node_w1[(size_t)(l * 256 + 128 + np) * 128 + t];
    vc[l * 128 + t] = s;
  }
}

// ---- counting sort of edges by target; rank = arrival order per target.
// rank is stored in S's memory (consumed by scatter before proj zeroes S). ----
__global__ void hist_kernel(const int* __restrict__ eidx, int* __restrict__ deg,
                            int* __restrict__ rnk, int E_) {
  int e = blockIdx.x * 256 + threadIdx.x;
  if (e < E_) rnk[e] = atomicAdd(&deg[eidx[E_ + e]], 1);
}

// ---- single-block exclusive scan of deg[n] -> off[n] (replaces 3 kernels) ----
__global__ __launch_bounds__(1024) void scan_kernel(const int* __restrict__ deg,
                                                    int* __restrict__ off, int n) {
  __shared__ int s[1024];
  const int t = threadIdx.x;
  const int chunk = (n + 1023) / 1024;
  int a = t * chunk;
  int b = a + chunk; if (b > n) b = n;
  int sum = 0;
#pragma unroll 4
  for (int i = a; i < b; i++) sum += deg[i];
  s[t] = sum;
  __syncthreads();
  for (int d = 1; d < 1024; d <<= 1) {
    int x = (t >= d) ? s[t - d] : 0;
    __syncthreads();
    s[t] += x;
    __syncthreads();
  }
  int pre = s[t] - sum;  // exclusive prefix of this thread's chunk
#pragma unroll 4
  for (int i = a; i < b; i++) { off[i] = pre; pre += deg[i]; }
}

// scatter edges into target-sorted order — NO atomics (rank precomputed).
// es16[p] = (src, tgt, dist_bits, 0): one aligned 16 B store, 1 line/edge.
__global__ void scatter_kernel(const int* __restrict__ eidx, const float* __restrict__ pos,
                               const int* __restrict__ off, const int* __restrict__ rnk,
                               int4* __restrict__ es16, int E_) {
  int e = blockIdx.x * 256 + threadIdx.x;
  if (e >= E_) return;
  int sr = eidx[e], tg = eidx[E_ + e];
  float dx = pos[sr * 3 + 0] - pos[tg * 3 + 0];
  float dy = pos[sr * 3 + 1] - pos[tg * 3 + 1];
  float dz = pos[sr * 3 + 2] - pos[tg * 3 + 2];
  float d = dx * dx + dy * dy + dz * dz;
  int p = off[tg] + rnk[e];
  int4 v;
  v.x = sr; v.y = tg; v.z = __float_as_int(d); v.w = 0;
  es16[p] = v;
}

// ---- proj (layer 0, embed fused): h = x*emb_w+emb_b; P = h@W1a + b1, Q = h@W1b.
// Also zeroes S (rank scratch is dead by now; edge layer 0 needs S = 0). ----
__global__ __launch_bounds__(256) void proj_kernel(
    const float* __restrict__ x, const float* __restrict__ emb_w,
    const float* __restrict__ emb_b, u16* __restrict__ hbf,
    u16* __restrict__ Pout, u16* __restrict__ Qout,
    const u16* __restrict__ pw, const float* __restrict__ b1,
    float* __restrict__ S, int NHtot, int nblocks, int nnodes) {
  __shared__ __align__(16) u16 s_A[TM * ASTRIDE];
  __shared__ __align__(16) u16 s_W[16384];
  const int t = threadIdx.x;
  const int w = t >> 6, lane = t & 63, quad = lane >> 4, m16 = lane & 15;
  const int tile0 = blockIdx.x * TM;
  {
    int id = blockIdx.x * 256 + t;
    int stride = nblocks * 256;
    for (int i = id; i < NHtot; i += stride) S[i] = 0.f;
  }
  {
    int r = t >> 2, qo = (t & 3) * 32;
    int node = tile0 + r;
    if (node >= nnodes) node = nnodes - 1;
    float xv = x[node];
    u16 hv[32];
#pragma unroll
    for (int i = 0; i < 32; i++) hv[i] = f2bf(xv * emb_w[qo + i] + emb_b[qo + i]);
    u16* dst = s_A + r * ASTRIDE + qo;
#pragma unroll
    for (int i = 0; i < 4; i++) *(int4*)(dst + i * 8) = *(int4*)(hv + i * 8);
    u16* gd = hbf + (size_t)node * HN + qo;
#pragma unroll
    for (int i = 0; i < 4; i++) *(int4*)(gd + i * 8) = *(int4*)(hv + i * 8);
  }
  {
    const int4* src = (const int4*)pw;
    int4* dst = (int4*)s_W;
#pragma unroll
    for (int i = 0; i < 8; i++) dst[t + i * 256] = src[t + i * 256];
  }
  __syncthreads();
  f32x4 acc[8];
#pragma unroll
  for (int ct = 0; ct < 8; ct++) acc[ct] = {0.f, 0.f, 0.f, 0.f};
  gemm64(s_A, s_W, w, quad, m16, acc);
  __syncthreads();
  {
    const int4* src = (const int4*)(pw + 16384);
    int4* dst = (int4*)s_W;
#pragma unroll
    for (int i = 0; i < 8; i++) dst[t + i * 256] = src[t + i * 256];
  }
  float bb[8];
#pragma unroll
  for (int ct = 0; ct < 8; ct++) bb[ct] = b1[ct * 16 + m16];
#pragma unroll
  for (int ct = 0; ct < 8; ct++)
#pragma unroll
    for (int j = 0; j < 4; j++) {
      int n = tile0 + w * 16 + quad * 4 + j;
      if (n < nnodes) Pout[n * HN + ct * 16 + m16] = f2bf(acc[ct][j] + bb[ct]);
    }
  __syncthreads();
#pragma unroll
  for (int ct = 0; ct < 8; ct++) acc[ct] = {0.f, 0.f, 0.f, 0.f};
  gemm64(s_A, s_W, w, quad, m16, acc);
#pragma unroll
  for (int ct = 0; ct < 8; ct++)
#pragma unroll
    for (int j = 0; j < 4; j++) {
      int n = tile0 + w * 16 + quad * 4 + j;
      if (n < nnodes) Qout[n * HN + ct * 16 + m16] = f2bf(acc[ct][j]);
    }
}

// ---- edge kernel: 2 cols/thread, 4 waves x 64 edges, 8-deep SW pipeline,
// scalarized segment state ----
__device__ __forceinline__ void edge_step(
    int tg_s, float dd_s, unsigned qv,
    int& cur_s, float& p0, float& p1, float& s0, float& s1,
    const u16* __restrict__ P, float* __restrict__ S, int cp,
    float wd0, float wd1, int tprev_s, int tnext_s) {
  if (tg_s != cur_s) {  // scalar branch (wave-uniform by construction)
    if (cur_s >= 0) {
      float* dst = &S[(size_t)cur_s * HN + cp];
      if (cur_s == tprev_s || cur_s == tnext_s) {
        atomicAdd(dst, s0);
        atomicAdd(dst + 1, s1);
      } else {
        float2 v = {s0, s1};
        *(float2*)dst = v;
      }
    }
    cur_s = tg_s; s0 = 0.f; s1 = 0.f;
    int cg = tg_s < 0 ? 0 : tg_s;
    unsigned pv = *(const unsigned*)&P[(size_t)cg * HN + cp];
    p0 = bflo(pv); p1 = bfhi(pv);
  }
  float x0 = p0 + bflo(qv) + dd_s * wd0;
  float x1 = p1 + bfhi(qv) + dd_s * wd1;
  s0 += silu_f(x0);
  s1 += silu_f(x1);
}

__global__ __launch_bounds__(256) void edge_kernel(
    const u16* __restrict__ P, const u16* __restrict__ Q,
    float* __restrict__ S, const float* __restrict__ w1d,
    const int4* __restrict__ es16, int E_) {
  __shared__ int s_src[ECH + 8];
  __shared__ int s_tgt[ECH + 8];
  __shared__ float s_dist[ECH + 8];

  const int t = threadIdx.x;
  const int e0 = blockIdx.x * ECH;
  {
    int e = e0 + t;
    if (e < E_) {
      int4 v = es16[e];
      s_src[t] = v.x;
      s_tgt[t] = v.y;
      s_dist[t] = __int_as_float(v.z);
    } else {
      s_src[t] = 0; s_tgt[t] = -1; s_dist[t] = 0.f;
    }
    if (t < 8) { s_src[ECH + t] = 0; s_tgt[ECH + t] = -1; s_dist[ECH + t] = 0.f; }
  }
  __syncthreads();

  const int lane = t & 63;
  const int w = t >> 6;
  const int cp = lane * 2;
  const int a = w * 64;
  const float2 wdv = *(const float2*)&w1d[cp];
  const float wd0 = wdv.x, wd1 = wdv.y;

  int tprev_s, tnext_s;
  if (w == 0) tprev_s = (e0 > 0) ? es16[e0 - 1].y : -2;
  else tprev_s = s_tgt[a - 1];
  if (w == 3) tnext_s = (e0 + ECH < E_) ? es16[e0 + ECH].y : -2;
  else tnext_s = s_tgt[a + 64];
  tprev_s = __builtin_amdgcn_readfirstlane(tprev_s);
  tnext_s = __builtin_amdgcn_readfirstlane(tnext_s);

  // prologue: first 8 edges
  int tg[8];
  float dd[8];
  unsigned qv[8];
#pragma unroll
  for (int j = 0; j < 8; j++) {
    tg[j] = s_tgt[a + j];
    dd[j] = s_dist[a + j];
    qv[j] = *(const unsigned*)&Q[(size_t)s_src[a + j] * HN + cp];
  }

  int cur_s = -1;
  float s0 = 0.f, s1 = 0.f, p0 = 0.f, p1 = 0.f;

#pragma unroll
  for (int i = a; i < a + 64; i += 8) {
    // prefetch group i+8 (pads make reads safe; results discarded on last group)
    int tgn[8];
    float ddn[8];
    unsigned qvn[8];
#pragma unroll
    for (int j = 0; j < 8; j++) {
      int idx = i + 8 + j;
      tgn[j] = s_tgt[idx];
      ddn[j] = s_dist[idx];
      qvn[j] = *(const unsigned*)&Q[(size_t)s_src[idx] * HN + cp];
    }
#pragma unroll
    for (int j = 0; j < 8; j++) {
      int tg_s = __builtin_amdgcn_readfirstlane(tg[j]);
      edge_step(tg_s, dd[j], qv[j], cur_s, p0, p1, s0, s1, P, S, cp, wd0, wd1, tprev_s, tnext_s);
    }
#pragma unroll
    for (int j = 0; j < 8; j++) { tg[j] = tgn[j]; dd[j] = ddn[j]; qv[j] = qvn[j]; }
  }

  if (cur_s >= 0) {
    float* dst = &S[(size_t)cur_s * HN + cp];
    if (cur_s == tprev_s || cur_s == tnext_s) {
      atomicAdd(dst, s0);
      atomicAdd(dst + 1, s1);
    } else {
      float2 v = {s0, s1};
      *(float2*)dst = v;
    }
  }
}

// ---- node MLP with folded aggr: pre = S@Wc + h@W1a + deg*vc + b1;
// h' = silu(pre)@nodeW2 + b2. FUSE: next-layer P/Q. !FUSE (last layer):
// skip hout, pool-reduce the h' tile into g (batch sorted). ----
template <bool FUSE>
__global__ __launch_bounds__(256) void node_kernel(
    const u16* __restrict__ hbf, float* __restrict__ S, const int* __restrict__ deg,
    u16* __restrict__ hout, const u16* __restrict__ pwc, const float* __restrict__ vc,
    const u16* __restrict__ pwn, const float* __restrict__ b1, const float* __restrict__ b2,
    const u16* __restrict__ pw_next, const float* __restrict__ b1_next,
    u16* __restrict__ Pout, u16* __restrict__ Qout,
    const int* __restrict__ batch, float* __restrict__ g, int nnodes) {
  __shared__ __align__(16) u16 s_A[TM * ASTRIDE];
  __shared__ __align__(16) u16 s_W[16384];
  __shared__ int s_b[TM];
  const int t = threadIdx.x;
  const int w = t >> 6, lane = t & 63, quad = lane >> 4, m16 = lane & 15;
  const int tile0 = blockIdx.x * TM;
  const int r_ = t >> 2, qo_ = (t & 3) * 32;
  int node_ = tile0 + r_;
  if (node_ >= nnodes) node_ = nnodes - 1;

  // ---- stage A: acc = S@Wc ----
  {
    const int4* src = (const int4*)pwc;
    int4* dst = (int4*)s_W;
#pragma unroll
    for (int i = 0; i < 8; i++) dst[t + i * 256] = src[t + i * 256];
  }
  {
    const float4* src = (const float4*)(S + (size_t)node_ * HN + qo_);
    u16* dst = s_A + r_ * ASTRIDE + qo_;  // wave-private rows
#pragma unroll
    for (int i = 0; i < 8; i++) {
      float4 v = src[i];
      ushort4 o;
      o.x = f2bf(v.x); o.y = f2bf(v.y); o.z = f2bf(v.z); o.w = f2bf(v.w);
      *(ushort4*)(dst + i * 4) = o;
    }
    // re-zero S for next layer (own reads done)
    float4 z = {0.f, 0.f, 0.f, 0.f};
    float4* zd = (float4*)(S + (size_t)node_ * HN + qo_);
#pragma unroll
    for (int i = 0; i < 8; i++) zd[i] = z;
  }
  if (!FUSE && t < TM) {
    int n = tile0 + t;
    s_b[t] = (n < nnodes) ? batch[n] : -1;
  }
  __syncthreads();

  f32x4 acc[8];
#pragma unroll
  for (int ct = 0; ct < 8; ct++) acc[ct] = {0.f, 0.f, 0.f, 0.f};
  gemm64(s_A, s_W, w, quad, m16, acc);
  __syncthreads();  // s_W reads done

  // ---- stage B: acc += h@W1a ----
  {
    const int4* src = (const int4*)pwn;  // nodeW1a
    int4* dst = (int4*)s_W;
#pragma unroll
    for (int i = 0; i < 8; i++) dst[t + i * 256] = src[t + i * 256];
  }
  {
    const int4* src = (const int4*)(hbf + (size_t)node_ * HN + qo_);
    int4* dst = (int4*)(s_A + r_ * ASTRIDE + qo_);  // wave-private rows
#pragma unroll
    for (int i = 0; i < 4; i++) dst[i] = src[i];
  }
  __syncthreads();
  gemm64(s_A, s_W, w, quad, m16, acc);
  __syncthreads();

  // ---- stage C: silu(acc + deg*vc + b1) -> s_A; acc2 = hidden@W2n ----
  {
    const int4* src = (const int4*)(pwn + 32768);  // nodeW2
    int4* dst = (int4*)s_W;
#pragma unroll
    for (int i = 0; i < 8; i++) dst[t + i * 256] = src[t + i * 256];
  }
  {
    float bb1[8], vcr[8];
#pragma unroll
    for (int ct = 0; ct < 8; ct++) {
      bb1[ct] = b1[ct * 16 + m16];
      vcr[ct] = vc[ct * 16 + m16];
    }
    float degv[4];
#pragma unroll
    for (int j = 0; j < 4; j++) {
      int n = tile0 + w * 16 + quad * 4 + j;
      if (n >= nnodes) n = nnodes - 1;
      degv[j] = (float)deg[n];
    }
#pragma unroll
    for (int ct = 0; ct < 8; ct++)
#pragma unroll
      for (int j = 0; j < 4; j++) {
        int row = w * 16 + quad * 4 + j;
        float xv = acc[ct][j] + bb1[ct] + degv[j] * vcr[ct];
        s_A[row * ASTRIDE + ct * 16 + m16] = f2bf(silu_f(xv));  // wave-private rows
      }
  }
  __syncthreads();

#pragma unroll
  for (int ct = 0; ct < 8; ct++) acc[ct] = {0.f, 0.f, 0.f, 0.f};
  gemm64(s_A, s_W, w, quad, m16, acc);

  float bb2[8];
#pragma unroll
  for (int ct = 0; ct < 8; ct++) bb2[ct] = b2[ct * 16 + m16];

  if (FUSE) {
#pragma unroll
    for (int ct = 0; ct < 8; ct++)
#pragma unroll
      for (int j = 0; j < 4; j++) {
        int row = w * 16 + quad * 4 + j;
        int n = tile0 + row;
        if (n < nnodes) hout[n * HN + ct * 16 + m16] = f2bf(acc[ct][j] + bb2[ct]);
      }
#pragma unroll
    for (int ct = 0; ct < 8; ct++)
#pragma unroll
      for (int j = 0; j < 4; j++) {
        int row = w * 16 + quad * 4 + j;
        s_A[row * ASTRIDE + ct * 16 + m16] = f2bf(acc[ct][j] + bb2[ct]);  // wave-private
      }
    __syncthreads();  // stage-C s_W reads done before overwrite
    {
      const int4* src = (const int4*)pw_next;  // msgW1a'
      int4* dst = (int4*)s_W;
#pragma unroll
      for (int i = 0; i < 8; i++) dst[t + i * 256] = src[t + i * 256];
    }
    __syncthreads();
#pragma unroll
    for (int ct = 0; ct < 8; ct++) acc[ct] = {0.f, 0.f, 0.f, 0.f};
    gemm64(s_A, s_W, w, quad, m16, acc);
    {
      float bbn[8];
#pragma unroll
      for (int ct = 0; ct < 8; ct++) bbn[ct] = b1_next[ct * 16 + m16];
#pragma unroll
      for (int ct = 0; ct < 8; ct++)
#pragma unroll
        for (int j = 0; j < 4; j++) {
          int n = tile0 + w * 16 + quad * 4 + j;
          if (n < nnodes) Pout[n * HN + ct * 16 + m16] = f2bf(acc[ct][j] + bbn[ct]);
        }
    }
    __syncthreads();
    {
      const int4* src = (const int4*)(pw_next + 16384);  // msgW1b'
      int4* dst = (int4*)s_W;
#pragma unroll
      for (int i = 0; i < 8; i++) dst[t + i * 256] = src[t + i * 256];
    }
    __syncthreads();
#pragma unroll
    for (int ct = 0; ct < 8; ct++) acc[ct] = {0.f, 0.f, 0.f, 0.f};
    gemm64(s_A, s_W, w, quad, m16, acc);
#pragma unroll
    for (int ct = 0; ct < 8; ct++)
#pragma unroll
      for (int j = 0; j < 4; j++) {
        int n = tile0 + w * 16 + quad * 4 + j;
        if (n < nnodes) Qout[n * HN + ct * 16 + m16] = f2bf(acc[ct][j]);
      }
  } else {
    // ---- last layer: stage h' into s_A (wave-private), pool-reduce into g ----
#pragma unroll
    for (int ct = 0; ct < 8; ct++)
#pragma unroll
      for (int j = 0; j < 4; j++) {
        int row = w * 16 + quad * 4 + j;
        s_A[row * ASTRIDE + ct * 16 + m16] = f2bf(acc[ct][j] + bb2[ct]);
      }
    __syncthreads();
    const int cp2 = (t & 63) * 2;  // col pair
    const int rg = t >> 6;         // rows rg*16 .. rg*16+16
    int cur = -1;
    float ss0 = 0.f, ss1 = 0.f;
#pragma unroll 4
    for (int i = 0; i < 16; i++) {
      int r = rg * 16 + i;
      int bbat = s_b[r];
      if (bbat < 0) break;  // sorted; -1 only at tail tile
      if (bbat != cur) {
        if (cur >= 0) {
          atomicAdd(&g[cur * HN + cp2], ss0);
          atomicAdd(&g[cur * HN + cp2 + 1], ss1);
        }
        cur = bbat; ss0 = 0.f; ss1 = 0.f;
      }
      unsigned v = *(const unsigned*)&s_A[r * ASTRIDE + cp2];
      ss0 += bflo(v);
      ss1 += bfhi(v);
    }
    if (cur >= 0) {
      atomicAdd(&g[cur * HN + cp2], ss0);
      atomicAdd(&g[cur * HN + cp2 + 1], ss1);
    }
  }
}

// ---- out: one block per graph, split-K halves + shuffle reduce ----
__global__ __launch_bounds__(64) void out_kernel(
    const float* __restrict__ g, const float* __restrict__ w1,
    const float* __restrict__ b1, const float* __restrict__ w2,
    const float* __restrict__ b2, float* __restrict__ out) {
  const int gi = blockIdx.x;
  const int t = threadIdx.x;
  const int c = t & 31, kh = t >> 5;
  float s = 0.f;
  for (int k = kh * 64; k < kh * 64 + 64; k++)
    s += g[gi * HN + k] * w1[k * 32 + c];
  s += __shfl_down(s, 32);
  float r = 0.f;
  if (kh == 0) r = silu_f(s + b1[c]) * w2[c];
  r += __shfl_down(r, 16);
  r += __shfl_down(r, 8);
  r += __shfl_down(r, 4);
  r += __shfl_down(r, 2);
  r += __shfl_down(r, 1);
  if (t == 0) out[gi] = r + b2[0];
}

extern "C" void kernel_launch(void* const* d_in, const int* in_sizes, int n_in,
                              void* d_out, int out_size, void* d_ws, size_t ws_size,
                              hipStream_t stream) {
  const float* x = (const float*)d_in[0];
  const float* pos = (const float*)d_in[1];
  const int* eidx = (const int*)d_in[2];
  const int* batch = (const int*)d_in[3];
  const float* emb_w = (const float*)d_in[4];
  const float* emb_b = (const float*)d_in[5];
  const float* msg_w1 = (const float*)d_in[6];
  const float* msg_b1 = (const float*)d_in[7];
  const float* msg_w2 = (const float*)d_in[8];
  const float* msg_b2 = (const float*)d_in[9];
  const float* node_w1 = (const float*)d_in[10];
  const float* node_b1 = (const float*)d_in[11];
  const float* node_w2 = (const float*)d_in[12];
  const float* node_b2 = (const float*)d_in[13];
  const float* out_w1 = (const float*)d_in[14];
  const float* out_b1 = (const float*)d_in[15];
  const float* out_w2 = (const float*)d_in[16];
  const float* out_b2 = (const float*)d_in[17];
  float* outp = (float*)d_out;

  const int N = 30000, E = 600000, G = 64;
  const size_t NH = (size_t)N * HN;

  u16* hA = (u16*)d_ws;                       // N*128 bf16
  u16* hB = hA + NH;                          // N*128 bf16
  u16* Pp = hB + NH;                          // N*128 bf16
  u16* Qp = Pp + NH;                          // N*128 bf16
  float* S = (float*)(Qp + NH);               // N*128 f32 (also rank scratch)
  int4* es16 = (int4*)(S + NH);               // E int4 (src,tgt,dist,pad)
  int* deg = (int*)(es16 + E);                // N
  int* off = deg + N;                         // N
  float* g = (float*)(off + N);               // 64*128 f32
  u16* pw = (u16*)(g + G * HN);               // 4*6*16384 bf16
  u16* pwc = pw + (size_t)4 * 6 * 16384;      // 4*16384 bf16 (folded Wc)
  float* vcb = (float*)(pwc + (size_t)4 * 16384);  // 4*128 f32
  int* rnk = (int*)S;                         // E ints, aliases S (dead before proj)

  const int NTB = (N + TM - 1) / TM;

  // pack + zero deg/g (replaces memsets)
  pack_weights<<<(4 * 6 * 16384 + 255) / 256, 256, 0, stream>>>(
      msg_w1, msg_w2, node_w1, node_w2, pw, deg, g, N, G * HN);
  fold_kernel<<<8, 256, 0, stream>>>(msg_w2, node_w1, msg_b2, pw, pwc, vcb);

  // counting sort by target (rank precomputed in hist -> atomic-free scatter)
  hist_kernel<<<(E + 255) / 256, 256, 0, stream>>>(eidx, deg, rnk, E);
  scan_kernel<<<1, 1024, 0, stream>>>(deg, off, N);
  scatter_kernel<<<(E + 255) / 256, 256, 0, stream>>>(eidx, pos, off, rnk, es16, E);

  // layer-0: embed + projections fused; also zeroes S (rank scratch dead now)
  proj_kernel<<<NTB, 256, 0, stream>>>(x, emb_w, emb_b, hA, Pp, Qp, pw, msg_b1,
                                       S, (int)NH, NTB, N);

  u16* hcur = hA;
  u16* hnext = hB;
  for (int l = 0; l < 4; l++) {
    const u16* pwl = pw + (size_t)(l * 6) * 16384;
    edge_kernel<<<(E + ECH - 1) / ECH, 256, 0, stream>>>(
        Pp, Qp, S,
        msg_w1 + (size_t)(l * 257 + 256) * 128,  // w1d row (fp32)
        es16, E);
    if (l < 3) {
      const u16* pw_next = pw + (size_t)((l + 1) * 6) * 16384;
      node_kernel<true><<<NTB, 256, 0, stream>>>(
          hcur, S, deg, hnext, pwc + (size_t)l * 16384, vcb + l * 128,
          pwl + 3 * 16384, node_b1 + l * 128, node_b2 + l * 128,
          pw_next, msg_b1 + (l + 1) * 128, Pp, Qp, nullptr, nullptr, N);
    } else {
      node_kernel<false><<<NTB, 256, 0, stream>>>(
          hcur, S, deg, hnext, pwc + (size_t)l * 16384, vcb + l * 128,
          pwl + 3 * 16384, node_b1 + l * 128, node_b2 + l * 128,
          nullptr, nullptr, nullptr, nullptr, batch, g, N);
    }
    u16* tmp = hcur; hcur = hnext; hnext = tmp;
  }

  out_kernel<<<G, 64, 0, stream>>>(g, out_w1, out_b1, out_w2, out_b2, outp);
}

// Round 18
// 401.636 us; speedup vs baseline: 1.0087x; 1.0087x over previous
//
#include <hip/hip_runtime.h>

typedef unsigned short u16;
typedef __bf16 bf16x8 __attribute__((ext_vector_type(8)));
typedef float f32x4 __attribute__((ext_vector_type(4)));

#define HN 128
#define TM 64
#define ASTRIDE 136   // 128 + 8 pad (u16), rows 16B-aligned
#define ECH 256       // edges per block in edge_kernel (4 waves x 64)

__device__ __forceinline__ u16 f2bf(float f) {
  union { float f; unsigned u; } v; v.f = f;
  unsigned r = v.u + 0x7fffu + ((v.u >> 16) & 1u);
  return (u16)(r >> 16);
}
__device__ __forceinline__ float bf2f(u16 v) {
  union { unsigned u; float f; } x; x.u = ((unsigned)v) << 16; return x.f;
}
__device__ __forceinline__ float bflo(unsigned v) {
  union { unsigned u; float f; } x; x.u = v << 16; return x.f;
}
__device__ __forceinline__ float bfhi(unsigned v) {
  union { unsigned u; float f; } x; x.u = v & 0xffff0000u; return x.f;
}
// fast silu: x * rcp(1 + exp2(-log2e*x)) — v_exp_f32/v_rcp_f32, ~1 ulp
__device__ __forceinline__ float silu_f(float x) {
  float e = __builtin_amdgcn_exp2f(-1.442695041f * x);
  return x * __builtin_amdgcn_rcpf(1.f + e);
}

// ---- pack weights into MFMA B-fragment layout: P[kg][n][8], kg=k/8 ----
// mats per layer: 0=msgW1a 1=msgW1b 2=msgW2 3=nodeW1a 4=nodeW1b 5=nodeW2
// Also zeroes deg[N] and g[G*HN].
__global__ void pack_weights(const float* __restrict__ msg_w1, const float* __restrict__ msg_w2,
                             const float* __restrict__ node_w1, const float* __restrict__ node_w2,
                             u16* __restrict__ pw, int* __restrict__ deg,
                             float* __restrict__ g, int N_, int GH) {
  int id = blockIdx.x * 256 + threadIdx.x;
  if (id < N_) deg[id] = 0;
  if (id < GH) g[id] = 0.f;
  if (id >= 4 * 6 * 16384) return;
  int l = id / (6 * 16384);
  int rem = id % (6 * 16384);
  int m = rem / 16384;
  int e = rem % 16384;
  int kg = e >> 10;
  int n = (e >> 3) & 127;
  int j = e & 7;
  int k = kg * 8 + j;
  float v = 0.f;
  switch (m) {
    case 0: v = msg_w1[(l * 257 + k) * 128 + n]; break;
    case 1: v = msg_w1[(l * 257 + 128 + k) * 128 + n]; break;
    case 2: v = msg_w2[(l * 128 + k) * 128 + n]; break;
    case 3: v = node_w1[(l * 256 + k) * 128 + n]; break;
    case 4: v = node_w1[(l * 256 + 128 + k) * 128 + n]; break;
    case 5: v = node_w2[(l * 128 + k) * 128 + n]; break;
  }
  pw[id] = f2bf(v);
}

__device__ __forceinline__ void gemm64(const u16* s_A, const u16* s_W,
                                       int w, int quad, int m16, f32x4 acc[8]) {
#pragma unroll
  for (int ks = 0; ks < 4; ks++) {
    bf16x8 a = *(const bf16x8*)&s_A[(w * 16 + m16) * ASTRIDE + ks * 32 + quad * 8];
#pragma unroll
    for (int ct = 0; ct < 8; ct++) {
      bf16x8 b = *(const bf16x8*)&s_W[(ks * 4 + quad) * 1024 + (ct * 16 + m16) * 8];
      acc[ct] = __builtin_amdgcn_mfma_f32_16x16x32_bf16(a, b, acc[ct], 0, 0, 0);
    }
  }
}

// ---- fold: Wc = msgW2 @ nodeW1b (bf16, B-frag packed), vc = msg_b2 @ nodeW1b ----
__global__ __launch_bounds__(256) void fold_kernel(
    const float* __restrict__ msg_w2, const float* __restrict__ node_w1,
    const float* __restrict__ msg_b2, const u16* __restrict__ pw,
    u16* __restrict__ pwc, float* __restrict__ vc) {
  __shared__ __align__(16) u16 s_A[TM * ASTRIDE];
  __shared__ __align__(16) u16 s_W[16384];
  const int t = threadIdx.x;
  const int w = t >> 6, lane = t & 63, quad = lane >> 4, m16 = lane & 15;
  const int b = blockIdx.x, l = b >> 1, half = b & 1;
  const int tile0 = half * 64;

  {
    int r = t >> 2, qo = (t & 3) * 32;
    const float4* src = (const float4*)(msg_w2 + (size_t)(l * 128 + tile0 + r) * 128 + qo);
    u16* dst = s_A + r * ASTRIDE + qo;
#pragma unroll
    for (int i = 0; i < 8; i++) {
      float4 v = src[i];
      ushort4 o;
      o.x = f2bf(v.x); o.y = f2bf(v.y); o.z = f2bf(v.z); o.w = f2bf(v.w);
      *(ushort4*)(dst + i * 4) = o;
    }
  }
  {
    const int4* src = (const int4*)(pw + (size_t)(l * 6 + 4) * 16384);
    int4* dst = (int4*)s_W;
#pragma unroll
    for (int i = 0; i < 8; i++) dst[t + i * 256] = src[t + i * 256];
  }
  __syncthreads();
  f32x4 acc[8];
#pragma unroll
  for (int ct = 0; ct < 8; ct++) acc[ct] = {0.f, 0.f, 0.f, 0.f};
  gemm64(s_A, s_W, w, quad, m16, acc);
#pragma unroll
  for (int ct = 0; ct < 8; ct++)
#pragma unroll
    for (int j = 0; j < 4; j++) {
      int k = tile0 + w * 16 + quad * 4 + j;
      int n = ct * 16 + m16;
      pwc[(size_t)l * 16384 + (k >> 3) * 1024 + n * 8 + (k & 7)] = f2bf(acc[ct][j]);
    }
  if (half == 0 && t < 128) {
    float s = 0.f;
    for (int np = 0; np < 128; np++)
      s += msg_b2[l * 128 + np] * node_w1[(size_t)(l * 256 + 128 + np) * 128 + t];
    vc[l * 128 + t] = s;
  }
}

// ---- counting sort of edges by target; rank = arrival order per target.
// rank is stored in S's memory (consumed by scatter before proj zeroes S). ----
__global__ void hist_kernel(const int* __restrict__ eidx, int* __restrict__ deg,
                            int* __restrict__ rnk, int E_) {
  int e = blockIdx.x * 256 + threadIdx.x;
  if (e < E_) rnk[e] = atomicAdd(&deg[eidx[E_ + e]], 1);
}

__global__ void scan1_kernel(const int* __restrict__ deg, int* __restrict__ off,
                             int* __restrict__ bsum, int n) {
  __shared__ int s[256];
  int t = threadIdx.x;
  int i = blockIdx.x * 256 + t;
  int v = (i < n) ? deg[i] : 0;
  s[t] = v;
  for (int d = 1; d < 256; d <<= 1) {
    __syncthreads();
    int x = (t >= d) ? s[t - d] : 0;
    __syncthreads();
    s[t] += x;
  }
  __syncthreads();
  if (i < n) off[i] = s[t] - v;
  if (t == 255) bsum[blockIdx.x] = s[255];
}

__global__ void scan2_kernel(int* __restrict__ bsum, int nb) {
  __shared__ int s[256];
  int t = threadIdx.x;
  int v = (t < nb) ? bsum[t] : 0;
  s[t] = v;
  for (int d = 1; d < 256; d <<= 1) {
    __syncthreads();
    int x = (t >= d) ? s[t - d] : 0;
    __syncthreads();
    s[t] += x;
  }
  __syncthreads();
  if (t < nb) bsum[t] = s[t] - v;  // exclusive block offsets
}

__global__ void scan3_kernel(int* __restrict__ off, const int* __restrict__ bsum, int n) {
  int i = blockIdx.x * 256 + threadIdx.x;
  if (i < n) off[i] += bsum[blockIdx.x];
}

// scatter edges into target-sorted order — NO atomics (rank precomputed).
// es16[p] = (src, tgt, dist_bits, 0): one aligned 16 B store, 1 line/edge.
__global__ void scatter_kernel(const int* __restrict__ eidx, const float* __restrict__ pos,
                               const int* __restrict__ off, const int* __restrict__ rnk,
                               int4* __restrict__ es16, int E_) {
  int e = blockIdx.x * 256 + threadIdx.x;
  if (e >= E_) return;
  int sr = eidx[e], tg = eidx[E_ + e];
  float dx = pos[sr * 3 + 0] - pos[tg * 3 + 0];
  float dy = pos[sr * 3 + 1] - pos[tg * 3 + 1];
  float dz = pos[sr * 3 + 2] - pos[tg * 3 + 2];
  float d = dx * dx + dy * dy + dz * dz;
  int p = off[tg] + rnk[e];
  int4 v;
  v.x = sr; v.y = tg; v.z = __float_as_int(d); v.w = 0;
  es16[p] = v;
}

// ---- proj (layer 0, embed fused): h = x*emb_w+emb_b; P = h@W1a + b1, Q = h@W1b.
// Also zeroes S (rank scratch is dead by now; edge layer 0 needs S = 0). ----
__global__ __launch_bounds__(256) void proj_kernel(
    const float* __restrict__ x, const float* __restrict__ emb_w,
    const float* __restrict__ emb_b, u16* __restrict__ hbf,
    u16* __restrict__ Pout, u16* __restrict__ Qout,
    const u16* __restrict__ pw, const float* __restrict__ b1,
    float* __restrict__ S, int NHtot, int nblocks, int nnodes) {
  __shared__ __align__(16) u16 s_A[TM * ASTRIDE];
  __shared__ __align__(16) u16 s_W[16384];
  const int t = threadIdx.x;
  const int w = t >> 6, lane = t & 63, quad = lane >> 4, m16 = lane & 15;
  const int tile0 = blockIdx.x * TM;
  {
    int id = blockIdx.x * 256 + t;
    int stride = nblocks * 256;
    for (int i = id; i < NHtot; i += stride) S[i] = 0.f;
  }
  {
    int r = t >> 2, qo = (t & 3) * 32;
    int node = tile0 + r;
    if (node >= nnodes) node = nnodes - 1;
    float xv = x[node];
    u16 hv[32];
#pragma unroll
    for (int i = 0; i < 32; i++) hv[i] = f2bf(xv * emb_w[qo + i] + emb_b[qo + i]);
    u16* dst = s_A + r * ASTRIDE + qo;
#pragma unroll
    for (int i = 0; i < 4; i++) *(int4*)(dst + i * 8) = *(int4*)(hv + i * 8);
    u16* gd = hbf + (size_t)node * HN + qo;
#pragma unroll
    for (int i = 0; i < 4; i++) *(int4*)(gd + i * 8) = *(int4*)(hv + i * 8);
  }
  {
    const int4* src = (const int4*)pw;
    int4* dst = (int4*)s_W;
#pragma unroll
    for (int i = 0; i < 8; i++) dst[t + i * 256] = src[t + i * 256];
  }
  __syncthreads();
  f32x4 acc[8];
#pragma unroll
  for (int ct = 0; ct < 8; ct++) acc[ct] = {0.f, 0.f, 0.f, 0.f};
  gemm64(s_A, s_W, w, quad, m16, acc);
  __syncthreads();
  {
    const int4* src = (const int4*)(pw + 16384);
    int4* dst = (int4*)s_W;
#pragma unroll
    for (int i = 0; i < 8; i++) dst[t + i * 256] = src[t + i * 256];
  }
  float bb[8];
#pragma unroll
  for (int ct = 0; ct < 8; ct++) bb[ct] = b1[ct * 16 + m16];
#pragma unroll
  for (int ct = 0; ct < 8; ct++)
#pragma unroll
    for (int j = 0; j < 4; j++) {
      int n = tile0 + w * 16 + quad * 4 + j;
      if (n < nnodes) Pout[n * HN + ct * 16 + m16] = f2bf(acc[ct][j] + bb[ct]);
    }
  __syncthreads();
#pragma unroll
  for (int ct = 0; ct < 8; ct++) acc[ct] = {0.f, 0.f, 0.f, 0.f};
  gemm64(s_A, s_W, w, quad, m16, acc);
#pragma unroll
  for (int ct = 0; ct < 8; ct++)
#pragma unroll
    for (int j = 0; j < 4; j++) {
      int n = tile0 + w * 16 + quad * 4 + j;
      if (n < nnodes) Qout[n * HN + ct * 16 + m16] = f2bf(acc[ct][j]);
    }
}

// ---- edge kernel: 2 cols/thread, 4 waves x 64 edges, 8-deep SW pipeline,
// scalarized segment state ----
__device__ __forceinline__ void edge_step(
    int tg_s, float dd_s, unsigned qv,
    int& cur_s, float& p0, float& p1, float& s0, float& s1,
    const u16* __restrict__ P, float* __restrict__ S, int cp,
    float wd0, float wd1, int tprev_s, int tnext_s) {
  if (tg_s != cur_s) {  // scalar branch (wave-uniform by construction)
    if (cur_s >= 0) {
      float* dst = &S[(size_t)cur_s * HN + cp];
      if (cur_s == tprev_s || cur_s == tnext_s) {
        atomicAdd(dst, s0);
        atomicAdd(dst + 1, s1);
      } else {
        float2 v = {s0, s1};
        *(float2*)dst = v;
      }
    }
    cur_s = tg_s; s0 = 0.f; s1 = 0.f;
    int cg = tg_s < 0 ? 0 : tg_s;
    unsigned pv = *(const unsigned*)&P[(size_t)cg * HN + cp];
    p0 = bflo(pv); p1 = bfhi(pv);
  }
  float x0 = p0 + bflo(qv) + dd_s * wd0;
  float x1 = p1 + bfhi(qv) + dd_s * wd1;
  s0 += silu_f(x0);
  s1 += silu_f(x1);
}

__global__ __launch_bounds__(256) void edge_kernel(
    const u16* __restrict__ P, const u16* __restrict__ Q,
    float* __restrict__ S, const float* __restrict__ w1d,
    const int4* __restrict__ es16, int E_) {
  __shared__ int s_src[ECH + 8];
  __shared__ int s_tgt[ECH + 8];
  __shared__ float s_dist[ECH + 8];

  const int t = threadIdx.x;
  const int e0 = blockIdx.x * ECH;
  {
    int e = e0 + t;
    if (e < E_) {
      int4 v = es16[e];
      s_src[t] = v.x;
      s_tgt[t] = v.y;
      s_dist[t] = __int_as_float(v.z);
    } else {
      s_src[t] = 0; s_tgt[t] = -1; s_dist[t] = 0.f;
    }
    if (t < 8) { s_src[ECH + t] = 0; s_tgt[ECH + t] = -1; s_dist[ECH + t] = 0.f; }
  }
  __syncthreads();

  const int lane = t & 63;
  const int w = t >> 6;
  const int cp = lane * 2;
  const int a = w * 64;
  const float2 wdv = *(const float2*)&w1d[cp];
  const float wd0 = wdv.x, wd1 = wdv.y;

  int tprev_s, tnext_s;
  if (w == 0) tprev_s = (e0 > 0) ? es16[e0 - 1].y : -2;
  else tprev_s = s_tgt[a - 1];
  if (w == 3) tnext_s = (e0 + ECH < E_) ? es16[e0 + ECH].y : -2;
  else tnext_s = s_tgt[a + 64];
  tprev_s = __builtin_amdgcn_readfirstlane(tprev_s);
  tnext_s = __builtin_amdgcn_readfirstlane(tnext_s);

  // prologue: first 8 edges
  int tg[8];
  float dd[8];
  unsigned qv[8];
#pragma unroll
  for (int j = 0; j < 8; j++) {
    tg[j] = s_tgt[a + j];
    dd[j] = s_dist[a + j];
    qv[j] = *(const unsigned*)&Q[(size_t)s_src[a + j] * HN + cp];
  }

  int cur_s = -1;
  float s0 = 0.f, s1 = 0.f, p0 = 0.f, p1 = 0.f;

#pragma unroll
  for (int i = a; i < a + 64; i += 8) {
    // prefetch group i+8 (pads make reads safe; results discarded on last group)
    int tgn[8];
    float ddn[8];
    unsigned qvn[8];
#pragma unroll
    for (int j = 0; j < 8; j++) {
      int idx = i + 8 + j;
      tgn[j] = s_tgt[idx];
      ddn[j] = s_dist[idx];
      qvn[j] = *(const unsigned*)&Q[(size_t)s_src[idx] * HN + cp];
    }
#pragma unroll
    for (int j = 0; j < 8; j++) {
      int tg_s = __builtin_amdgcn_readfirstlane(tg[j]);
      edge_step(tg_s, dd[j], qv[j], cur_s, p0, p1, s0, s1, P, S, cp, wd0, wd1, tprev_s, tnext_s);
    }
#pragma unroll
    for (int j = 0; j < 8; j++) { tg[j] = tgn[j]; dd[j] = ddn[j]; qv[j] = qvn[j]; }
  }

  if (cur_s >= 0) {
    float* dst = &S[(size_t)cur_s * HN + cp];
    if (cur_s == tprev_s || cur_s == tnext_s) {
      atomicAdd(dst, s0);
      atomicAdd(dst + 1, s1);
    } else {
      float2 v = {s0, s1};
      *(float2*)dst = v;
    }
  }
}

// ---- node MLP with folded aggr: pre = S@Wc + h@W1a + deg*vc + b1;
// h' = silu(pre)@nodeW2 + b2; FUSE: next-layer P/Q ----
template <bool FUSE>
__global__ __launch_bounds__(256) void node_kernel(
    const u16* __restrict__ hbf, float* __restrict__ S, const int* __restrict__ deg,
    u16* __restrict__ hout, const u16* __restrict__ pwc, const float* __restrict__ vc,
    const u16* __restrict__ pwn, const float* __restrict__ b1, const float* __restrict__ b2,
    const u16* __restrict__ pw_next, const float* __restrict__ b1_next,
    u16* __restrict__ Pout, u16* __restrict__ Qout, int nnodes) {
  __shared__ __align__(16) u16 s_A[TM * ASTRIDE];
  __shared__ __align__(16) u16 s_W[16384];
  const int t = threadIdx.x;
  const int w = t >> 6, lane = t & 63, quad = lane >> 4, m16 = lane & 15;
  const int tile0 = blockIdx.x * TM;
  const int r_ = t >> 2, qo_ = (t & 3) * 32;
  int node_ = tile0 + r_;
  if (node_ >= nnodes) node_ = nnodes - 1;

  // ---- stage A: acc = S@Wc ----
  {
    const int4* src = (const int4*)pwc;
    int4* dst = (int4*)s_W;
#pragma unroll
    for (int i = 0; i < 8; i++) dst[t + i * 256] = src[t + i * 256];
  }
  {
    const float4* src = (const float4*)(S + (size_t)node_ * HN + qo_);
    u16* dst = s_A + r_ * ASTRIDE + qo_;  // wave-private rows
#pragma unroll
    for (int i = 0; i < 8; i++) {
      float4 v = src[i];
      ushort4 o;
      o.x = f2bf(v.x); o.y = f2bf(v.y); o.z = f2bf(v.z); o.w = f2bf(v.w);
      *(ushort4*)(dst + i * 4) = o;
    }
    // re-zero S for next layer (own reads done)
    float4 z = {0.f, 0.f, 0.f, 0.f};
    float4* zd = (float4*)(S + (size_t)node_ * HN + qo_);
#pragma unroll
    for (int i = 0; i < 8; i++) zd[i] = z;
  }
  __syncthreads();

  f32x4 acc[8];
#pragma unroll
  for (int ct = 0; ct < 8; ct++) acc[ct] = {0.f, 0.f, 0.f, 0.f};
  gemm64(s_A, s_W, w, quad, m16, acc);
  __syncthreads();  // s_W reads done

  // ---- stage B: acc += h@W1a ----
  {
    const int4* src = (const int4*)pwn;  // nodeW1a
    int4* dst = (int4*)s_W;
#pragma unroll
    for (int i = 0; i < 8; i++) dst[t + i * 256] = src[t + i * 256];
  }
  {
    const int4* src = (const int4*)(hbf + (size_t)node_ * HN + qo_);
    int4* dst = (int4*)(s_A + r_ * ASTRIDE + qo_);  // wave-private rows
#pragma unroll
    for (int i = 0; i < 4; i++) dst[i] = src[i];
  }
  __syncthreads();
  gemm64(s_A, s_W, w, quad, m16, acc);
  __syncthreads();

  // ---- stage C: silu(acc + deg*vc + b1) -> s_A; acc2 = hidden@W2n ----
  {
    const int4* src = (const int4*)(pwn + 32768);  // nodeW2
    int4* dst = (int4*)s_W;
#pragma unroll
    for (int i = 0; i < 8; i++) dst[t + i * 256] = src[t + i * 256];
  }
  {
    float bb1[8], vcr[8];
#pragma unroll
    for (int ct = 0; ct < 8; ct++) {
      bb1[ct] = b1[ct * 16 + m16];
      vcr[ct] = vc[ct * 16 + m16];
    }
    float degv[4];
#pragma unroll
    for (int j = 0; j < 4; j++) {
      int n = tile0 + w * 16 + quad * 4 + j;
      if (n >= nnodes) n = nnodes - 1;
      degv[j] = (float)deg[n];
    }
#pragma unroll
    for (int ct = 0; ct < 8; ct++)
#pragma unroll
      for (int j = 0; j < 4; j++) {
        int row = w * 16 + quad * 4 + j;
        float xv = acc[ct][j] + bb1[ct] + degv[j] * vcr[ct];
        s_A[row * ASTRIDE + ct * 16 + m16] = f2bf(silu_f(xv));  // wave-private rows
      }
  }
  __syncthreads();

#pragma unroll
  for (int ct = 0; ct < 8; ct++) acc[ct] = {0.f, 0.f, 0.f, 0.f};
  gemm64(s_A, s_W, w, quad, m16, acc);

  float bb2[8];
#pragma unroll
  for (int ct = 0; ct < 8; ct++) bb2[ct] = b2[ct * 16 + m16];
#pragma unroll
  for (int ct = 0; ct < 8; ct++)
#pragma unroll
    for (int j = 0; j < 4; j++) {
      int row = w * 16 + quad * 4 + j;
      int n = tile0 + row;
      if (n < nnodes) hout[n * HN + ct * 16 + m16] = f2bf(acc[ct][j] + bb2[ct]);
    }

  if (FUSE) {
#pragma unroll
    for (int ct = 0; ct < 8; ct++)
#pragma unroll
      for (int j = 0; j < 4; j++) {
        int row = w * 16 + quad * 4 + j;
        s_A[row * ASTRIDE + ct * 16 + m16] = f2bf(acc[ct][j] + bb2[ct]);  // wave-private
      }
    __syncthreads();  // stage-C s_W reads done before overwrite
    {
      const int4* src = (const int4*)pw_next;  // msgW1a'
      int4* dst = (int4*)s_W;
#pragma unroll
      for (int i = 0; i < 8; i++) dst[t + i * 256] = src[t + i * 256];
    }
    __syncthreads();
#pragma unroll
    for (int ct = 0; ct < 8; ct++) acc[ct] = {0.f, 0.f, 0.f, 0.f};
    gemm64(s_A, s_W, w, quad, m16, acc);
    {
      float bbn[8];
#pragma unroll
      for (int ct = 0; ct < 8; ct++) bbn[ct] = b1_next[ct * 16 + m16];
#pragma unroll
      for (int ct = 0; ct < 8; ct++)
#pragma unroll
        for (int j = 0; j < 4; j++) {
          int n = tile0 + w * 16 + quad * 4 + j;
          if (n < nnodes) Pout[n * HN + ct * 16 + m16] = f2bf(acc[ct][j] + bbn[ct]);
        }
    }
    __syncthreads();
    {
      const int4* src = (const int4*)(pw_next + 16384);  // msgW1b'
      int4* dst = (int4*)s_W;
#pragma unroll
      for (int i = 0; i < 8; i++) dst[t + i * 256] = src[t + i * 256];
    }
    __syncthreads();
#pragma unroll
    for (int ct = 0; ct < 8; ct++) acc[ct] = {0.f, 0.f, 0.f, 0.f};
    gemm64(s_A, s_W, w, quad, m16, acc);
#pragma unroll
    for (int ct = 0; ct < 8; ct++)
#pragma unroll
      for (int j = 0; j < 4; j++) {
        int n = tile0 + w * 16 + quad * 4 + j;
        if (n < nnodes) Qout[n * HN + ct * 16 + m16] = f2bf(acc[ct][j]);
      }
  }
}

// ---- pool: 469 blocks x 256 thr; thread = (colpair, rowgroup of 16) ----
__global__ __launch_bounds__(256) void pool_kernel(
    const u16* __restrict__ h, const int* __restrict__ batch,
    float* __restrict__ g, int N) {
  __shared__ int s_b[64];
  const int t = threadIdx.x;
  const int n0 = blockIdx.x * 64;
  if (t < 64) {
    int n = n0 + t;
    s_b[t] = (n < N) ? batch[n] : -1;
  }
  __syncthreads();
  const int cp = (t & 63) * 2;
  const int rg = t >> 6;
  int cur = -1;
  float s0 = 0.f, s1 = 0.f;
#pragma unroll 4
  for (int i = 0; i < 16; i++) {
    int r = rg * 16 + i;
    int b = s_b[r];
    if (b < 0) break;  // sorted; -1 only at tail
    if (b != cur) {
      if (cur >= 0) {
        atomicAdd(&g[cur * HN + cp], s0);
        atomicAdd(&g[cur * HN + cp + 1], s1);
      }
      cur = b; s0 = 0.f; s1 = 0.f;
    }
    unsigned v = *(const unsigned*)&h[(size_t)(n0 + r) * HN + cp];
    s0 += bf2f((u16)(v & 0xffffu));
    s1 += bf2f((u16)(v >> 16));
  }
  if (cur >= 0) {
    atomicAdd(&g[cur * HN + cp], s0);
    atomicAdd(&g[cur * HN + cp + 1], s1);
  }
}

// ---- out: one block per graph, split-K halves + shuffle reduce ----
__global__ __launch_bounds__(64) void out_kernel(
    const float* __restrict__ g, const float* __restrict__ w1,
    const float* __restrict__ b1, const float* __restrict__ w2,
    const float* __restrict__ b2, float* __restrict__ out) {
  const int gi = blockIdx.x;
  const int t = threadIdx.x;
  const int c = t & 31, kh = t >> 5;
  float s = 0.f;
  for (int k = kh * 64; k < kh * 64 + 64; k++)
    s += g[gi * HN + k] * w1[k * 32 + c];
  s += __shfl_down(s, 32);
  float r = 0.f;
  if (kh == 0) r = silu_f(s + b1[c]) * w2[c];
  r += __shfl_down(r, 16);
  r += __shfl_down(r, 8);
  r += __shfl_down(r, 4);
  r += __shfl_down(r, 2);
  r += __shfl_down(r, 1);
  if (t == 0) out[gi] = r + b2[0];
}

extern "C" void kernel_launch(void* const* d_in, const int* in_sizes, int n_in,
                              void* d_out, int out_size, void* d_ws, size_t ws_size,
                              hipStream_t stream) {
  const float* x = (const float*)d_in[0];
  const float* pos = (const float*)d_in[1];
  const int* eidx = (const int*)d_in[2];
  const int* batch = (const int*)d_in[3];
  const float* emb_w = (const float*)d_in[4];
  const float* emb_b = (const float*)d_in[5];
  const float* msg_w1 = (const float*)d_in[6];
  const float* msg_b1 = (const float*)d_in[7];
  const float* msg_w2 = (const float*)d_in[8];
  const float* msg_b2 = (const float*)d_in[9];
  const float* node_w1 = (const float*)d_in[10];
  const float* node_b1 = (const float*)d_in[11];
  const float* node_w2 = (const float*)d_in[12];
  const float* node_b2 = (const float*)d_in[13];
  const float* out_w1 = (const float*)d_in[14];
  const float* out_b1 = (const float*)d_in[15];
  const float* out_w2 = (const float*)d_in[16];
  const float* out_b2 = (const float*)d_in[17];
  float* outp = (float*)d_out;

  const int N = 30000, E = 600000, G = 64;
  const size_t NH = (size_t)N * HN;

  u16* hA = (u16*)d_ws;                       // N*128 bf16
  u16* hB = hA + NH;                          // N*128 bf16
  u16* Pp = hB + NH;                          // N*128 bf16
  u16* Qp = Pp + NH;                          // N*128 bf16
  float* S = (float*)(Qp + NH);               // N*128 f32 (also rank scratch)
  int4* es16 = (int4*)(S + NH);               // E int4 (src,tgt,dist,pad)
  int* deg = (int*)(es16 + E);                // N
  int* off = deg + N;                         // N
  int* bsum = off + N;                        // 128
  float* g = (float*)(bsum + 128);            // 64*128 f32
  u16* pw = (u16*)(g + G * HN);               // 4*6*16384 bf16
  u16* pwc = pw + (size_t)4 * 6 * 16384;      // 4*16384 bf16 (folded Wc)
  float* vcb = (float*)(pwc + (size_t)4 * 16384);  // 4*128 f32
  int* rnk = (int*)S;                         // E ints, aliases S (dead before proj)

  const int NB = (N + 255) / 256;
  const int NTB = (N + TM - 1) / TM;

  // pack + zero deg/g (replaces memsets)
  pack_weights<<<(4 * 6 * 16384 + 255) / 256, 256, 0, stream>>>(
      msg_w1, msg_w2, node_w1, node_w2, pw, deg, g, N, G * HN);
  fold_kernel<<<8, 256, 0, stream>>>(msg_w2, node_w1, msg_b2, pw, pwc, vcb);

  // counting sort by target (rank precomputed in hist -> atomic-free scatter)
  hist_kernel<<<(E + 255) / 256, 256, 0, stream>>>(eidx, deg, rnk, E);
  scan1_kernel<<<NB, 256, 0, stream>>>(deg, off, bsum, N);
  scan2_kernel<<<1, 256, 0, stream>>>(bsum, NB);
  scan3_kernel<<<NB, 256, 0, stream>>>(off, bsum, N);
  scatter_kernel<<<(E + 255) / 256, 256, 0, stream>>>(eidx, pos, off, rnk, es16, E);

  // layer-0: embed + projections fused; also zeroes S (rank scratch dead now)
  proj_kernel<<<NTB, 256, 0, stream>>>(x, emb_w, emb_b, hA, Pp, Qp, pw, msg_b1,
                                       S, (int)NH, NTB, N);

  u16* hcur = hA;
  u16* hnext = hB;
  for (int l = 0; l < 4; l++) {
    const u16* pwl = pw + (size_t)(l * 6) * 16384;
    edge_kernel<<<(E + ECH - 1) / ECH, 256, 0, stream>>>(
        Pp, Qp, S,
        msg_w1 + (size_t)(l * 257 + 256) * 128,  // w1d row (fp32)
        es16, E);
    if (l < 3) {
      const u16* pw_next = pw + (size_t)((l + 1) * 6) * 16384;
      node_kernel<true><<<NTB, 256, 0, stream>>>(
          hcur, S, deg, hnext, pwc + (size_t)l * 16384, vcb + l * 128,
          pwl + 3 * 16384, node_b1 + l * 128, node_b2 + l * 128,
          pw_next, msg_b1 + (l + 1) * 128, Pp, Qp, N);
    } else {
      node_kernel<false><<<NTB, 256, 0, stream>>>(
          hcur, S, deg, hnext, pwc + (size_t)l * 16384, vcb + l * 128,
          pwl + 3 * 16384, node_b1 + l * 128, node_b2 + l * 128,
          nullptr, nullptr, nullptr, nullptr, N);
    }
    u16* tmp = hcur; hcur = hnext; hnext = tmp;
  }

  pool_kernel<<<(N + 63) / 64, 256, 0, stream>>>(hcur, batch, g, N);
  out_kernel<<<G, 64, 0, stream>>>(g, out_w1, out_b1, out_w2, out_b2, outp);
}